// Round 6
// baseline (218.059 us; speedup 1.0000x reference)
//
#include <hip/hip_runtime.h>
#include <hip/hip_bf16.h>
#include <stdint.h>

// B=4096, H=256, K=16, D=512 (8*64)
#define NB   4096
#define NH   256
#define NK   16
#define ND   512

using short8  = __attribute__((ext_vector_type(8))) short;
using float4v = __attribute__((ext_vector_type(4))) float;

__device__ __forceinline__ float fast_tanh(float x) {
  float e = __builtin_amdgcn_exp2f(x * 2.88539008177793f);
  return 1.0f - 2.0f * __builtin_amdgcn_rcpf(e + 1.0f);
}

__device__ __forceinline__ unsigned short f2bf(float f) {
  union { float f; unsigned u; } v; v.f = f;
  unsigned r = v.u + 0x7FFF + ((v.u >> 16) & 1);  // RNE, inputs finite
  return (unsigned short)(r >> 16);
}

__device__ __forceinline__ float bf2f(unsigned short h) {
  union { unsigned u; float f; } v; v.u = ((unsigned)h) << 16; return v.f;
}

// ------------------------------------------------------------- prep ----
// blocks [0,1024): w2 -> B2[k][kk][e][32] (transposed K-major bf16)
// blocks [1024,1536): gating softmax
__global__ __launch_bounds__(256) void k_prep(
    const float* __restrict__ w2, const float* __restrict__ h_prev,
    const float* __restrict__ gw1, const float* __restrict__ gb1,
    const float* __restrict__ gw2, const float* __restrict__ gb2,
    unsigned short* __restrict__ B2, float* __restrict__ gates) {
  __shared__ float sbuf[4160];
  const int t = threadIdx.x;
  const int lin = blockIdx.x;

  if (lin < 1024) {
    const int w = lin;
    const int e0 = (w & 7) * 64;
    const int d0 = ((w >> 3) & 7) * 64;
    const int k = w >> 6;
    float (*sh)[65] = (float(*)[65])sbuf;
    const float* src = w2 + ((size_t)k * ND + d0) * ND + e0;
#pragma unroll
    for (int rep = 0; rep < 4; ++rep) {
      int r = rep * 16 + (t >> 4);
      int c = (t & 15) * 4;
      float4 v = *(const float4*)&src[(size_t)r * ND + c];
      sh[r][c] = v.x; sh[r][c + 1] = v.y; sh[r][c + 2] = v.z; sh[r][c + 3] = v.w;
    }
    __syncthreads();
#pragma unroll
    for (int s = 0; s < 2; ++s) {
      int idx = t + s * 256;
      int kh = idx >> 8;
      int rem = idx & 255;
      int e = e0 + (rem >> 2);
      int c8 = (rem & 3) * 8;
      int kk = (d0 >> 5) + kh;
      unsigned short o[8];
#pragma unroll
      for (int j = 0; j < 8; ++j) o[j] = f2bf(sh[kh * 32 + c8 + j][e - e0]);
      *(uint4*)&B2[(((size_t)(k * 16 + kk)) * ND + e) * 32 + c8] = *(uint4*)o;
    }
  } else {
    const int b0 = (lin - 1024) * 8;
    float* sh_h = sbuf;
    float* sh_t = sbuf + 2048;
    for (int r = 0; r < 8; ++r) sh_h[r * 256 + t] = h_prev[(b0 + r) * NH + t];
    __syncthreads();
    float acc[8];
    float bias = gb1[t];
#pragma unroll
    for (int r = 0; r < 8; ++r) acc[r] = bias;
    for (int i = 0; i < NH; i += 4) {
      float w0 = gw1[(i + 0) * NH + t];
      float w1v = gw1[(i + 1) * NH + t];
      float w2v = gw1[(i + 2) * NH + t];
      float w3 = gw1[(i + 3) * NH + t];
#pragma unroll
      for (int r = 0; r < 8; ++r) {
        float4 hv = *(const float4*)&sh_h[r * 256 + i];
        acc[r] += hv.x * w0 + hv.y * w1v + hv.z * w2v + hv.w * w3;
      }
    }
#pragma unroll
    for (int r = 0; r < 8; ++r) sh_t[t * 8 + r] = fast_tanh(acc[r]);
    __syncthreads();
    if (t < 128) {
      const int r = t >> 4, k = t & 15;
      float lg = gb2[k];
      for (int j = 0; j < NH; ++j) lg += sh_t[j * 8 + r] * gw2[j * NK + k];
      float m = lg;
      for (int off = 1; off < 16; off <<= 1) m = fmaxf(m, __shfl_xor(m, off, 16));
      float e = __builtin_amdgcn_exp2f((lg - m) * 1.44269504f);
      float s = e;
      for (int off = 1; off < 16; off <<= 1) s += __shfl_xor(s, off, 16);
      gates[(b0 + r) * NK + k] = e * __builtin_amdgcn_rcpf(s);
    }
  }
}

// ------------------------------------------------------------------ GEMM ----
// Fused GEMM: whole A-tile (h1, 128x512 bf16 = 128KB) generated ONCE into LDS
// behind a single barrier; K-loop is barrier-free (A read-only in LDS, B
// direct-to-register from L2-resident B2 with a 2-slot ring loaded 2 iters
// ahead -> fine-grained vmcnt pipelining). Epilogue fuses bias+tanh+LN+gate,
// reuses sA as the transpose buffer. Block: 512 thr (2m x 4n waves), M=128,
// N=512, 1 block/CU (LDS-bound).
__global__ __launch_bounds__(512) void k_gemm(
    const float* __restrict__ x_ext, const float* __restrict__ w1,
    const float* __restrict__ b1,
    const unsigned short* __restrict__ B2,    // [K*16][512e][32k]
    const float* __restrict__ b2,             // [K][512]
    const float* __restrict__ gates,          // [B][16]
    const float* __restrict__ ln_g, const float* __restrict__ ln_b,
    unsigned short* __restrict__ h2ln) {      // [B][K][512]
  __shared__ __align__(16) unsigned short sA[16 * 128 * 32];  // 128 KB
  __shared__ float ps[4][128][2];                             // 4 KB
  __shared__ __align__(16) float fin[128][4];                 // 2 KB

  const int t = threadIdx.x;
  const int l = t & 63, w = t >> 6;
  const int wm = w & 1, wn = w >> 1;          // 2m x 4n wave grid
  const int q = l >> 4, m16 = l & 15;

  const int lin = blockIdx.x;                 // 512 blocks
  const int ke = (lin & 7) * 2 + (lin >> 8);  // XCD-phased expert
  const int m0 = ((lin >> 3) & 31) * 128;

  // --- B ring: direct-to-register, contiguous 1KB frags from L2 ---
  const unsigned short* Bbase =
      B2 + ((size_t)(ke * 16)) * (ND * 32) + (wn * 128 + m16) * 32 + q * 8;
  short8 bf[2][8];
  auto loadB = [&](int kk, int slot) {
#pragma unroll
    for (int bni = 0; bni < 8; ++bni)
      bf[slot][bni] = *(const short8*)(Bbase + (size_t)kk * (ND * 32) + bni * 512);
  };
  loadB(0, 0);
  loadB(1, 1);

  // --- A-gen: whole 128x512 h1 tile, once ---
  {
    const int r = t >> 2, ac8 = (t & 3) * 8;
    const float x = x_ext[(m0 + r) * NK + ke];
    const float* w1k = w1 + ke * ND;
    const float* b1k = b1 + ke * ND;
#pragma unroll
    for (int kk = 0; kk < 16; ++kk) {
      const int d = kk * 32 + ac8;
      float4 wlo = *(const float4*)&w1k[d];
      float4 whi = *(const float4*)&w1k[d + 4];
      float4 blo = *(const float4*)&b1k[d];
      float4 bhi = *(const float4*)&b1k[d + 4];
      unsigned short o[8];
      o[0] = f2bf(fast_tanh(x * wlo.x + blo.x));
      o[1] = f2bf(fast_tanh(x * wlo.y + blo.y));
      o[2] = f2bf(fast_tanh(x * wlo.z + blo.z));
      o[3] = f2bf(fast_tanh(x * wlo.w + blo.w));
      o[4] = f2bf(fast_tanh(x * whi.x + bhi.x));
      o[5] = f2bf(fast_tanh(x * whi.y + bhi.y));
      o[6] = f2bf(fast_tanh(x * whi.z + bhi.z));
      o[7] = f2bf(fast_tanh(x * whi.w + bhi.w));
      *(uint4*)&sA[kk * 4096 + r * 32 + ac8] = *(uint4*)o;
    }
  }
  __syncthreads();  // the ONLY barrier before the epilogue

  float4v acc[4][8];
#pragma unroll
  for (int f = 0; f < 4; ++f)
#pragma unroll
    for (int bni = 0; bni < 8; ++bni) acc[f][bni] = (float4v){0.f, 0.f, 0.f, 0.f};

  // --- barrier-free K-loop ---
#pragma unroll
  for (int kk = 0; kk < 16; ++kk) {
    const int cur = kk & 1;
    short8 af[4];
#pragma unroll
    for (int f = 0; f < 4; ++f)
      af[f] = *(const short8*)&sA[kk * 4096 + (wm * 64 + f * 16 + m16) * 32 + q * 8];
#pragma unroll
    for (int f = 0; f < 4; ++f)
#pragma unroll
      for (int bni = 0; bni < 8; ++bni)
        acc[f][bni] = __builtin_amdgcn_mfma_f32_16x16x32_bf16(
            af[f], bf[cur][bni], acc[f][bni], 0, 0, 0);
    if (kk < 14) loadB(kk + 2, cur);  // refill the slot just consumed
  }

  // ---- epilogue: h2 = tanh(acc + b2); LN over 512 cols; gate-scale ----
  float b2v[8], gld[8], lbd[8];
#pragma unroll
  for (int bni = 0; bni < 8; ++bni) {
    int n = wn * 128 + bni * 16 + m16;
    b2v[bni] = b2[ke * ND + n];
    gld[bni] = ln_g[n];
    lbd[bni] = ln_b[n];
  }
#pragma unroll
  for (int f = 0; f < 4; ++f)
#pragma unroll
    for (int bni = 0; bni < 8; ++bni)
#pragma unroll
      for (int rr = 0; rr < 4; ++rr)
        acc[f][bni][rr] = fast_tanh(acc[f][bni][rr] + b2v[bni]);

  // per-row partial sums over this wave's 128 cols
  float s1v[4][4], s2v[4][4];
#pragma unroll
  for (int f = 0; f < 4; ++f)
#pragma unroll
    for (int rr = 0; rr < 4; ++rr) {
      float s = 0.f, s2 = 0.f;
#pragma unroll
      for (int bni = 0; bni < 8; ++bni) {
        float v = acc[f][bni][rr];
        s += v; s2 += v * v;
      }
#pragma unroll
      for (int off = 1; off < 16; off <<= 1) {
        s += __shfl_xor(s, off, 64);
        s2 += __shfl_xor(s2, off, 64);
      }
      s1v[f][rr] = s; s2v[f][rr] = s2;
    }
  if (m16 == 0) {
#pragma unroll
    for (int f = 0; f < 4; ++f)
#pragma unroll
      for (int rr = 0; rr < 4; ++rr) {
        int row = wm * 64 + f * 16 + q * 4 + rr;
        *(float2*)&ps[wn][row][0] = (float2){s1v[f][rr], s2v[f][rr]};
      }
  }
  __syncthreads();
  if (t < 128) {
    float s  = ps[0][t][0] + ps[1][t][0] + ps[2][t][0] + ps[3][t][0];
    float s2 = ps[0][t][1] + ps[1][t][1] + ps[2][t][1] + ps[3][t][1];
    float mu = s * (1.f / 512.f);
    float var = s2 * (1.f / 512.f) - mu * mu;
    float rs = __builtin_amdgcn_rsqf(var + 1e-5f);
    float gate = gates[(m0 + t) * NK + ke];
    fin[t][0] = mu; fin[t][1] = gate * rs; fin[t][2] = gate; fin[t][3] = 0.f;
  }

  // 4 transpose passes (tp buffer reuses sA) -> coalesced bf16 stores
  unsigned short* tp = sA;  // 128 x 136 ushorts = 34.8 KB
#pragma unroll
  for (int cq = 0; cq < 4; ++cq) {
    __syncthreads();  // fin visible; tp safe to overwrite
    if (wn == cq) {
#pragma unroll
      for (int f = 0; f < 4; ++f)
#pragma unroll
        for (int rr = 0; rr < 4; ++rr) {
          int row = wm * 64 + f * 16 + q * 4 + rr;
          float4 fr = *(float4*)&fin[row][0];
#pragma unroll
          for (int bni = 0; bni < 8; ++bni) {
            float v = fr.y * gld[bni] * (acc[f][bni][rr] - fr.x) + fr.z * lbd[bni];
            tp[row * 136 + bni * 16 + m16] = f2bf(v);
          }
        }
    }
    __syncthreads();
#pragma unroll
    for (int it = 0; it < 4; ++it) {
      int idx = it * 512 + t;
      int row = idx >> 4;
      int c8 = (idx & 15) * 8;
      *(uint4*)&h2ln[((size_t)(m0 + row) * NK + ke) * ND + cq * 128 + c8] =
          *(uint4*)&tp[row * 136 + c8];
    }
  }
}

// ---------------------------------------------- plane-sum + x_prime ----
__global__ __launch_bounds__(256) void k_final(
    const unsigned short* __restrict__ h2ln,  // [B][K][512]
    const float* __restrict__ x_l,            // [B][8]
    const float* __restrict__ theta0,         // [512]
    float* __restrict__ out) {
  const int t = threadIdx.x;
  const int l = t & 63;
  const int b = blockIdx.x * 4 + (t >> 6);
  const int d0 = l * 8;
  const unsigned short* P = h2ln + (size_t)b * NK * ND + d0;
  uint4 raw[16];
#pragma unroll
  for (int k = 0; k < NK; ++k) raw[k] = *(const uint4*)&P[k * ND];
  float acc[8];
#pragma unroll
  for (int j = 0; j < 8; ++j) acc[j] = 0.f;
#pragma unroll
  for (int k = 0; k < NK; ++k) {
    const unsigned short* hp = (const unsigned short*)&raw[k];
#pragma unroll
    for (int j = 0; j < 8; ++j) acc[j] += bf2f(hp[j]);
  }
  float th[8];
  *(float4*)&th[0] = *(const float4*)&theta0[d0];
  *(float4*)&th[4] = *(const float4*)&theta0[d0 + 4];
#pragma unroll
  for (int j = 0; j < 8; ++j) th[j] += acc[j];
  float* thp = out + (size_t)NB * 64 + (size_t)b * ND + d0;
  *(float4*)&thp[0] = *(float4*)&th[0];
  *(float4*)&thp[4] = *(float4*)&th[4];
  const float xl = x_l[b * 8 + (l >> 3)];
  float p[8];
#pragma unroll
  for (int j = 0; j < 8; ++j) p[j] = xl * th[j];
  for (int off = 8; off < 64; off <<= 1)
#pragma unroll
    for (int j = 0; j < 8; ++j) p[j] += __shfl_xor(p[j], off, 64);
  if (l < 8) {
    float* xp = out + (size_t)b * 64 + l * 8;
    *(float4*)&xp[0] = *(float4*)&p[0];
    *(float4*)&xp[4] = *(float4*)&p[4];
  }
}

// ----------------------------------------------------------------- launch ----
extern "C" void kernel_launch(void* const* d_in, const int* in_sizes, int n_in,
                              void* d_out, int out_size, void* d_ws, size_t ws_size,
                              hipStream_t stream) {
  const float* h_prev = (const float*)d_in[0];
  const float* x_l    = (const float*)d_in[1];
  const float* x_ext  = (const float*)d_in[2];
  const float* mw1    = (const float*)d_in[3];
  const float* mb1    = (const float*)d_in[4];
  const float* mw2    = (const float*)d_in[5];
  const float* mb2    = (const float*)d_in[6];
  const float* gw1    = (const float*)d_in[7];
  const float* gb1    = (const float*)d_in[8];
  const float* gw2    = (const float*)d_in[9];
  const float* gb2    = (const float*)d_in[10];
  const float* ln_g   = (const float*)d_in[11];
  const float* ln_b   = (const float*)d_in[12];
  const float* th0    = (const float*)d_in[13];
  float* out = (float*)d_out;

  char* ws = (char*)d_ws;
  float* gates = (float*)ws;                                        // 256 KB
  unsigned short* B2   = (unsigned short*)(ws + (1u << 18));        // 8 MB
  unsigned short* h2ln = (unsigned short*)(ws + (1u << 18) + (16u << 20));  // 64 MB

  hipLaunchKernelGGL(k_prep, dim3(1536), dim3(256), 0, stream,
                     mw2, h_prev, gw1, gb1, gw2, gb2, B2, gates);
  hipLaunchKernelGGL(k_gemm, dim3(512), dim3(512), 0, stream,
                     x_ext, mw1, mb1, B2, mb2, gates, ln_g, ln_b, h2ln);
  hipLaunchKernelGGL(k_final, dim3(NB / 4), dim3(256), 0, stream,
                     h2ln, x_l, th0, out);
}

// Round 7
// 209.803 us; speedup vs baseline: 1.0394x; 1.0394x over previous
//
#include <hip/hip_runtime.h>
#include <hip/hip_bf16.h>
#include <stdint.h>

// B=4096, H=256, K=16, D=512 (8*64)
#define NB   4096
#define NH   256
#define NK   16
#define ND   512

using short8  = __attribute__((ext_vector_type(8))) short;
using float4v = __attribute__((ext_vector_type(4))) float;

__device__ __forceinline__ float fast_tanh(float x) {
  float e = __builtin_amdgcn_exp2f(x * 2.88539008177793f);
  return 1.0f - 2.0f * __builtin_amdgcn_rcpf(e + 1.0f);
}

__device__ __forceinline__ unsigned short f2bf(float f) {
  union { float f; unsigned u; } v; v.f = f;
  unsigned r = v.u + 0x7FFF + ((v.u >> 16) & 1);  // RNE, inputs finite
  return (unsigned short)(r >> 16);
}

__device__ __forceinline__ float bf2f(unsigned short h) {
  union { unsigned u; float f; } v; v.u = ((unsigned)h) << 16; return v.f;
}

// ------------------------------------------------------------- prep ----
// blocks [0,1024): w2 -> B2[k][kk][e][32] (transposed K-major bf16)
// blocks [1024,1536): gating softmax
__global__ __launch_bounds__(256) void k_prep(
    const float* __restrict__ w2, const float* __restrict__ h_prev,
    const float* __restrict__ gw1, const float* __restrict__ gb1,
    const float* __restrict__ gw2, const float* __restrict__ gb2,
    unsigned short* __restrict__ B2, float* __restrict__ gates) {
  __shared__ float sbuf[4160];
  const int t = threadIdx.x;
  const int lin = blockIdx.x;

  if (lin < 1024) {
    const int w = lin;
    const int e0 = (w & 7) * 64;
    const int d0 = ((w >> 3) & 7) * 64;
    const int k = w >> 6;
    float (*sh)[65] = (float(*)[65])sbuf;
    const float* src = w2 + ((size_t)k * ND + d0) * ND + e0;
#pragma unroll
    for (int rep = 0; rep < 4; ++rep) {
      int r = rep * 16 + (t >> 4);
      int c = (t & 15) * 4;
      float4 v = *(const float4*)&src[(size_t)r * ND + c];
      sh[r][c] = v.x; sh[r][c + 1] = v.y; sh[r][c + 2] = v.z; sh[r][c + 3] = v.w;
    }
    __syncthreads();
#pragma unroll
    for (int s = 0; s < 2; ++s) {
      int idx = t + s * 256;
      int kh = idx >> 8;
      int rem = idx & 255;
      int e = e0 + (rem >> 2);
      int c8 = (rem & 3) * 8;
      int kk = (d0 >> 5) + kh;
      unsigned short o[8];
#pragma unroll
      for (int j = 0; j < 8; ++j) o[j] = f2bf(sh[kh * 32 + c8 + j][e - e0]);
      *(uint4*)&B2[(((size_t)(k * 16 + kk)) * ND + e) * 32 + c8] = *(uint4*)o;
    }
  } else {
    const int b0 = (lin - 1024) * 8;
    float* sh_h = sbuf;
    float* sh_t = sbuf + 2048;
    for (int r = 0; r < 8; ++r) sh_h[r * 256 + t] = h_prev[(b0 + r) * NH + t];
    __syncthreads();
    float acc[8];
    float bias = gb1[t];
#pragma unroll
    for (int r = 0; r < 8; ++r) acc[r] = bias;
    for (int i = 0; i < NH; i += 4) {
      float w0 = gw1[(i + 0) * NH + t];
      float w1v = gw1[(i + 1) * NH + t];
      float w2v = gw1[(i + 2) * NH + t];
      float w3 = gw1[(i + 3) * NH + t];
#pragma unroll
      for (int r = 0; r < 8; ++r) {
        float4 hv = *(const float4*)&sh_h[r * 256 + i];
        acc[r] += hv.x * w0 + hv.y * w1v + hv.z * w2v + hv.w * w3;
      }
    }
#pragma unroll
    for (int r = 0; r < 8; ++r) sh_t[t * 8 + r] = fast_tanh(acc[r]);
    __syncthreads();
    if (t < 128) {
      const int r = t >> 4, k = t & 15;
      float lg = gb2[k];
      for (int j = 0; j < NH; ++j) lg += sh_t[j * 8 + r] * gw2[j * NK + k];
      float m = lg;
      for (int off = 1; off < 16; off <<= 1) m = fmaxf(m, __shfl_xor(m, off, 16));
      float e = __builtin_amdgcn_exp2f((lg - m) * 1.44269504f);
      float s = e;
      for (int off = 1; off < 16; off <<= 1) s += __shfl_xor(s, off, 16);
      gates[(b0 + r) * NK + k] = e * __builtin_amdgcn_rcpf(s);
    }
  }
}

// ------------------------------------------------------------------ GEMM ----
// Fused GEMM (R6 structure + register diet). A-tile (h1, 128x512 bf16) built
// once in LDS behind a single barrier; barrier-free K-loop with B in a 2-slot
// register ring from L2-resident B2. Epilogue: tanh+LN+gate with TRANSIENT
// row-sum reduction and DEFERRED ln_g/ln_b loads so lifetimes never stack on
// the 128-reg accumulator (R5/R6 spilled ~34 regs -> 36MB scratch traffic).
__global__ __launch_bounds__(512, 2) void k_gemm(
    const float* __restrict__ x_ext, const float* __restrict__ w1,
    const float* __restrict__ b1,
    const unsigned short* __restrict__ B2,    // [K*16][512e][32k]
    const float* __restrict__ b2,             // [K][512]
    const float* __restrict__ gates,          // [B][16]
    const float* __restrict__ ln_g, const float* __restrict__ ln_b,
    unsigned short* __restrict__ h2ln) {      // [B][K][512]
  __shared__ __align__(16) unsigned short sA[16 * 128 * 32];  // 128 KB
  __shared__ float ps[4][128][2];                             // 4 KB
  __shared__ __align__(16) float fin[128][4];                 // 2 KB

  const int t = threadIdx.x;
  const int l = t & 63, w = t >> 6;
  const int wm = w & 1, wn = w >> 1;          // 2m x 4n wave grid
  const int q = l >> 4, m16 = l & 15;

  const int lin = blockIdx.x;                 // 512 blocks
  const int ke = (lin & 7) * 2 + (lin >> 8);  // XCD-phased expert
  const int m0 = ((lin >> 3) & 31) * 128;

  // --- B ring: direct-to-register, contiguous 1KB frags from L2 ---
  const unsigned short* Bbase =
      B2 + ((size_t)(ke * 16)) * (ND * 32) + (wn * 128 + m16) * 32 + q * 8;
  short8 bf[2][8];
  auto loadB = [&](int kk, int slot) {
#pragma unroll
    for (int bni = 0; bni < 8; ++bni)
      bf[slot][bni] = *(const short8*)(Bbase + (size_t)kk * (ND * 32) + bni * 512);
  };
  loadB(0, 0);
  loadB(1, 1);

  // --- A-gen: whole 128x512 h1 tile, once ---
  {
    const int r = t >> 2, ac8 = (t & 3) * 8;
    const float x = x_ext[(m0 + r) * NK + ke];
    const float* w1k = w1 + ke * ND;
    const float* b1k = b1 + ke * ND;
#pragma unroll
    for (int kk = 0; kk < 16; ++kk) {
      const int d = kk * 32 + ac8;
      float4 wlo = *(const float4*)&w1k[d];
      float4 whi = *(const float4*)&w1k[d + 4];
      float4 blo = *(const float4*)&b1k[d];
      float4 bhi = *(const float4*)&b1k[d + 4];
      unsigned short o[8];
      o[0] = f2bf(fast_tanh(x * wlo.x + blo.x));
      o[1] = f2bf(fast_tanh(x * wlo.y + blo.y));
      o[2] = f2bf(fast_tanh(x * wlo.z + blo.z));
      o[3] = f2bf(fast_tanh(x * wlo.w + blo.w));
      o[4] = f2bf(fast_tanh(x * whi.x + bhi.x));
      o[5] = f2bf(fast_tanh(x * whi.y + bhi.y));
      o[6] = f2bf(fast_tanh(x * whi.z + bhi.z));
      o[7] = f2bf(fast_tanh(x * whi.w + bhi.w));
      *(uint4*)&sA[kk * 4096 + r * 32 + ac8] = *(uint4*)o;
    }
  }
  __syncthreads();  // the ONLY barrier before the epilogue

  float4v acc[4][8];
#pragma unroll
  for (int f = 0; f < 4; ++f)
#pragma unroll
    for (int bni = 0; bni < 8; ++bni) acc[f][bni] = (float4v){0.f, 0.f, 0.f, 0.f};

  // --- barrier-free K-loop ---
#pragma unroll
  for (int kk = 0; kk < 16; ++kk) {
    const int cur = kk & 1;
    short8 af[4];
#pragma unroll
    for (int f = 0; f < 4; ++f)
      af[f] = *(const short8*)&sA[kk * 4096 + (wm * 64 + f * 16 + m16) * 32 + q * 8];
#pragma unroll
    for (int f = 0; f < 4; ++f)
#pragma unroll
      for (int bni = 0; bni < 8; ++bni)
        acc[f][bni] = __builtin_amdgcn_mfma_f32_16x16x32_bf16(
            af[f], bf[cur][bni], acc[f][bni], 0, 0, 0);
    if (kk < 14) loadB(kk + 2, cur);  // refill the slot just consumed
  }

  // ---- epilogue: h2 = tanh(acc + b2), in place ----
  {
    float b2v[8];
#pragma unroll
    for (int bni = 0; bni < 8; ++bni) b2v[bni] = b2[ke * ND + wn * 128 + bni * 16 + m16];
#pragma unroll
    for (int f = 0; f < 4; ++f)
#pragma unroll
      for (int bni = 0; bni < 8; ++bni)
#pragma unroll
        for (int rr = 0; rr < 4; ++rr)
          acc[f][bni][rr] = fast_tanh(acc[f][bni][rr] + b2v[bni]);
  }

  // per-row partial sums over this wave's 128 cols -- TRANSIENT s/s2
#pragma unroll
  for (int f = 0; f < 4; ++f)
#pragma unroll
    for (int rr = 0; rr < 4; ++rr) {
      float s = 0.f, s2 = 0.f;
#pragma unroll
      for (int bni = 0; bni < 8; ++bni) {
        float v = acc[f][bni][rr];
        s += v; s2 += v * v;
      }
#pragma unroll
      for (int off = 1; off < 16; off <<= 1) {
        s += __shfl_xor(s, off, 64);
        s2 += __shfl_xor(s2, off, 64);
      }
      if (m16 == 0) {
        int row = wm * 64 + f * 16 + q * 4 + rr;
        *(float2*)&ps[wn][row][0] = (float2){s, s2};
      }
    }
  __syncthreads();
  if (t < 128) {
    float s  = ps[0][t][0] + ps[1][t][0] + ps[2][t][0] + ps[3][t][0];
    float s2 = ps[0][t][1] + ps[1][t][1] + ps[2][t][1] + ps[3][t][1];
    float mu = s * (1.f / 512.f);
    float var = s2 * (1.f / 512.f) - mu * mu;
    float rs = __builtin_amdgcn_rsqf(var + 1e-5f);
    float gate = gates[(m0 + t) * NK + ke];
    fin[t][0] = mu; fin[t][1] = gate * rs; fin[t][2] = gate; fin[t][3] = 0.f;
  }

  // ln_g/ln_b loaded HERE (bf ring dead, acc-only pressure)
  float gld[8], lbd[8];
#pragma unroll
  for (int bni = 0; bni < 8; ++bni) {
    int n = wn * 128 + bni * 16 + m16;
    gld[bni] = ln_g[n];
    lbd[bni] = ln_b[n];
  }

  // 4 transpose passes (tp buffer reuses sA) -> coalesced bf16 stores
  unsigned short* tp = sA;  // 128 x 136 ushorts = 34.8 KB
#pragma unroll
  for (int cq = 0; cq < 4; ++cq) {
    __syncthreads();  // fin visible; tp safe to overwrite
    if (wn == cq) {
#pragma unroll
      for (int f = 0; f < 4; ++f)
#pragma unroll
        for (int rr = 0; rr < 4; ++rr) {
          int row = wm * 64 + f * 16 + q * 4 + rr;
          float4 fr = *(float4*)&fin[row][0];
#pragma unroll
          for (int bni = 0; bni < 8; ++bni) {
            float v = fr.y * gld[bni] * (acc[f][bni][rr] - fr.x) + fr.z * lbd[bni];
            tp[row * 136 + bni * 16 + m16] = f2bf(v);
          }
        }
    }
    __syncthreads();
#pragma unroll
    for (int it = 0; it < 4; ++it) {
      int idx = it * 512 + t;
      int row = idx >> 4;
      int c8 = (idx & 15) * 8;
      *(uint4*)&h2ln[((size_t)(m0 + row) * NK + ke) * ND + cq * 128 + c8] =
          *(uint4*)&tp[row * 136 + c8];
    }
  }
}

// ---------------------------------------------- plane-sum + x_prime ----
__global__ __launch_bounds__(256) void k_final(
    const unsigned short* __restrict__ h2ln,  // [B][K][512]
    const float* __restrict__ x_l,            // [B][8]
    const float* __restrict__ theta0,         // [512]
    float* __restrict__ out) {
  const int t = threadIdx.x;
  const int l = t & 63;
  const int b = blockIdx.x * 4 + (t >> 6);
  const int d0 = l * 8;
  const unsigned short* P = h2ln + (size_t)b * NK * ND + d0;
  uint4 raw[16];
#pragma unroll
  for (int k = 0; k < NK; ++k) raw[k] = *(const uint4*)&P[k * ND];
  float acc[8];
#pragma unroll
  for (int j = 0; j < 8; ++j) acc[j] = 0.f;
#pragma unroll
  for (int k = 0; k < NK; ++k) {
    const unsigned short* hp = (const unsigned short*)&raw[k];
#pragma unroll
    for (int j = 0; j < 8; ++j) acc[j] += bf2f(hp[j]);
  }
  float th[8];
  *(float4*)&th[0] = *(const float4*)&theta0[d0];
  *(float4*)&th[4] = *(const float4*)&theta0[d0 + 4];
#pragma unroll
  for (int j = 0; j < 8; ++j) th[j] += acc[j];
  float* thp = out + (size_t)NB * 64 + (size_t)b * ND + d0;
  *(float4*)&thp[0] = *(float4*)&th[0];
  *(float4*)&thp[4] = *(float4*)&th[4];
  const float xl = x_l[b * 8 + (l >> 3)];
  float p[8];
#pragma unroll
  for (int j = 0; j < 8; ++j) p[j] = xl * th[j];
  for (int off = 8; off < 64; off <<= 1)
#pragma unroll
    for (int j = 0; j < 8; ++j) p[j] += __shfl_xor(p[j], off, 64);
  if (l < 8) {
    float* xp = out + (size_t)b * 64 + l * 8;
    *(float4*)&xp[0] = *(float4*)&p[0];
    *(float4*)&xp[4] = *(float4*)&p[4];
  }
}

// ----------------------------------------------------------------- launch ----
extern "C" void kernel_launch(void* const* d_in, const int* in_sizes, int n_in,
                              void* d_out, int out_size, void* d_ws, size_t ws_size,
                              hipStream_t stream) {
  const float* h_prev = (const float*)d_in[0];
  const float* x_l    = (const float*)d_in[1];
  const float* x_ext  = (const float*)d_in[2];
  const float* mw1    = (const float*)d_in[3];
  const float* mb1    = (const float*)d_in[4];
  const float* mw2    = (const float*)d_in[5];
  const float* mb2    = (const float*)d_in[6];
  const float* gw1    = (const float*)d_in[7];
  const float* gb1    = (const float*)d_in[8];
  const float* gw2    = (const float*)d_in[9];
  const float* gb2    = (const float*)d_in[10];
  const float* ln_g   = (const float*)d_in[11];
  const float* ln_b   = (const float*)d_in[12];
  const float* th0    = (const float*)d_in[13];
  float* out = (float*)d_out;

  char* ws = (char*)d_ws;
  float* gates = (float*)ws;                                        // 256 KB
  unsigned short* B2   = (unsigned short*)(ws + (1u << 18));        // 8 MB
  unsigned short* h2ln = (unsigned short*)(ws + (1u << 18) + (16u << 20));  // 64 MB

  hipLaunchKernelGGL(k_prep, dim3(1536), dim3(256), 0, stream,
                     mw2, h_prev, gw1, gb1, gw2, gb2, B2, gates);
  hipLaunchKernelGGL(k_gemm, dim3(512), dim3(512), 0, stream,
                     x_ext, mw1, mb1, B2, mb2, gates, ln_g, ln_b, h2ln);
  hipLaunchKernelGGL(k_final, dim3(NB / 4), dim3(256), 0, stream,
                     h2ln, x_l, th0, out);
}

// Round 8
// 193.026 us; speedup vs baseline: 1.1297x; 1.0869x over previous
//
#include <hip/hip_runtime.h>
#include <hip/hip_bf16.h>
#include <stdint.h>

// B=4096, H=256, K=16, D=512 (8*64)
#define NB   4096
#define NH   256
#define NK   16
#define ND   512

using short8  = __attribute__((ext_vector_type(8))) short;
using float4v = __attribute__((ext_vector_type(4))) float;
typedef unsigned short ushort;

__device__ __forceinline__ float fast_tanh(float x) {
  float e = __builtin_amdgcn_exp2f(x * 2.88539008177793f);
  return 1.0f - 2.0f * __builtin_amdgcn_rcpf(e + 1.0f);
}

__device__ __forceinline__ ushort f2bf(float f) {
  union { float f; unsigned u; } v; v.f = f;
  unsigned r = v.u + 0x7FFF + ((v.u >> 16) & 1);  // RNE, inputs finite
  return (ushort)(r >> 16);
}

__device__ __forceinline__ float bf2f(ushort h) {
  union { unsigned u; float f; } v; v.u = ((unsigned)h) << 16; return v.f;
}

__device__ __forceinline__ unsigned pk2(float a, float b) {
  __hip_bfloat162 h = __float22bfloat162_rn(float2{a, b});  // v_cvt_pk_bf16_f32
  unsigned u; __builtin_memcpy(&u, &h, 4); return u;
}

// ------------------------------------------------------------- prep ----
// blocks [0,1024): w2 -> B2[k][kk][e][32] (transposed K-major bf16)
// blocks [1024,1536): gating softmax
__global__ __launch_bounds__(256) void k_prep(
    const float* __restrict__ w2, const float* __restrict__ h_prev,
    const float* __restrict__ gw1, const float* __restrict__ gb1,
    const float* __restrict__ gw2, const float* __restrict__ gb2,
    ushort* __restrict__ B2, float* __restrict__ gates) {
  __shared__ float sbuf[4160];
  const int t = threadIdx.x;
  const int lin = blockIdx.x;

  if (lin < 1024) {
    const int w = lin;
    const int e0 = (w & 7) * 64;
    const int d0 = ((w >> 3) & 7) * 64;
    const int k = w >> 6;
    float (*sh)[65] = (float(*)[65])sbuf;
    const float* src = w2 + ((size_t)k * ND + d0) * ND + e0;
#pragma unroll
    for (int rep = 0; rep < 4; ++rep) {
      int r = rep * 16 + (t >> 4);
      int c = (t & 15) * 4;
      float4 v = *(const float4*)&src[(size_t)r * ND + c];
      sh[r][c] = v.x; sh[r][c + 1] = v.y; sh[r][c + 2] = v.z; sh[r][c + 3] = v.w;
    }
    __syncthreads();
#pragma unroll
    for (int s = 0; s < 2; ++s) {
      int idx = t + s * 256;
      int kh = idx >> 8;
      int rem = idx & 255;
      int e = e0 + (rem >> 2);
      int c8 = (rem & 3) * 8;
      int kk = (d0 >> 5) + kh;
      ushort o[8];
#pragma unroll
      for (int j = 0; j < 8; ++j) o[j] = f2bf(sh[kh * 32 + c8 + j][e - e0]);
      *(uint4*)&B2[(((size_t)(k * 16 + kk)) * ND + e) * 32 + c8] = *(uint4*)o;
    }
  } else {
    const int b0 = (lin - 1024) * 8;
    float* sh_h = sbuf;
    float* sh_t = sbuf + 2048;
    for (int r = 0; r < 8; ++r) sh_h[r * 256 + t] = h_prev[(b0 + r) * NH + t];
    __syncthreads();
    float acc[8];
    float bias = gb1[t];
#pragma unroll
    for (int r = 0; r < 8; ++r) acc[r] = bias;
    for (int i = 0; i < NH; i += 4) {
      float w0 = gw1[(i + 0) * NH + t];
      float w1v = gw1[(i + 1) * NH + t];
      float w2v = gw1[(i + 2) * NH + t];
      float w3 = gw1[(i + 3) * NH + t];
#pragma unroll
      for (int r = 0; r < 8; ++r) {
        float4 hv = *(const float4*)&sh_h[r * 256 + i];
        acc[r] += hv.x * w0 + hv.y * w1v + hv.z * w2v + hv.w * w3;
      }
    }
#pragma unroll
    for (int r = 0; r < 8; ++r) sh_t[t * 8 + r] = fast_tanh(acc[r]);
    __syncthreads();
    if (t < 128) {
      const int r = t >> 4, k = t & 15;
      float lg = gb2[k];
      for (int j = 0; j < NH; ++j) lg += sh_t[j * 8 + r] * gw2[j * NK + k];
      float m = lg;
      for (int off = 1; off < 16; off <<= 1) m = fmaxf(m, __shfl_xor(m, off, 16));
      float e = __builtin_amdgcn_exp2f((lg - m) * 1.44269504f);
      float s = e;
      for (int off = 1; off < 16; off <<= 1) s += __shfl_xor(s, off, 16);
      gates[(b0 + r) * NK + k] = e * __builtin_amdgcn_rcpf(s);
    }
  }
}

// ------------------------------------------------------------------ GEMM ----
// M=64 tile, 256 thr (4 waves, 1m x 4n), ~72KB LDS -> 2 blocks/CU so one
// block's A-gen (VALU) overlaps the other's K-loop (MFMA). A-tile (h1) built
// once into swizzle-padded LDS (row stride 36); barrier-free K-loop, B in a
// 2-slot register ring from L2-resident B2. Epilogue: tanh only (LN moved to
// k_final), single all-wave transpose (stride 524), coalesced bf16 stores.
__global__ __launch_bounds__(256, 2) void k_gemm(
    const float* __restrict__ x_ext, const float* __restrict__ w1,
    const float* __restrict__ b1,
    const ushort* __restrict__ B2,            // [K*16][512e][32k]
    const float* __restrict__ b2,             // [K][512]
    ushort* __restrict__ h2raw) {             // [B][K][512] = tanh(h2)
  __shared__ __align__(16) ushort smem[16 * 64 * 36];  // 72 KB (union sA/tp)
  ushort* sA = smem;   // [16 kk][64 r][36]
  ushort* tp = smem;   // [64 r][524]

  const int t = threadIdx.x;
  const int l = t & 63, w = t >> 6;           // 4 waves
  const int wn = w;                           // n-quarter
  const int q = l >> 4, m16 = l & 15;

  const int lin = blockIdx.x;                 // 1024 blocks
  const int xcd = lin & 7;
  const int slot = lin >> 3;                  // 0..127
  const int ke = xcd * 2 + (slot >> 6);       // XCD-phased expert
  const int m0 = (slot & 63) * 64;

  // --- B ring: direct-to-register, contiguous 1KB frags from L2 ---
  const ushort* Bbase =
      B2 + ((size_t)(ke * 16)) * (ND * 32) + (wn * 128 + m16) * 32 + q * 8;
  short8 bf[2][8];
  auto loadB = [&](int kk, int slotr) {
#pragma unroll
    for (int bni = 0; bni < 8; ++bni)
      bf[slotr][bni] = *(const short8*)(Bbase + (size_t)kk * (ND * 32) + bni * 512);
  };
  loadB(0, 0);
  loadB(1, 1);

  // --- A-gen: whole 64x512 h1 tile, once, packed cvt ---
  {
    const int r = t >> 2, ac8 = (t & 3) * 8;
    const float x = x_ext[(m0 + r) * NK + ke];
    const float* w1k = w1 + ke * ND;
    const float* b1k = b1 + ke * ND;
#pragma unroll
    for (int kk = 0; kk < 16; ++kk) {
      const int d = kk * 32 + ac8;
      float4 wlo = *(const float4*)&w1k[d];
      float4 whi = *(const float4*)&w1k[d + 4];
      float4 blo = *(const float4*)&b1k[d];
      float4 bhi = *(const float4*)&b1k[d + 4];
      unsigned o4[4];
      o4[0] = pk2(fast_tanh(x * wlo.x + blo.x), fast_tanh(x * wlo.y + blo.y));
      o4[1] = pk2(fast_tanh(x * wlo.z + blo.z), fast_tanh(x * wlo.w + blo.w));
      o4[2] = pk2(fast_tanh(x * whi.x + bhi.x), fast_tanh(x * whi.y + bhi.y));
      o4[3] = pk2(fast_tanh(x * whi.z + bhi.z), fast_tanh(x * whi.w + bhi.w));
      *(uint4*)&sA[kk * 2304 + r * 36 + ac8] = *(uint4*)o4;
    }
  }
  __syncthreads();

  float4v acc[4][8];
#pragma unroll
  for (int f = 0; f < 4; ++f)
#pragma unroll
    for (int bni = 0; bni < 8; ++bni) acc[f][bni] = (float4v){0.f, 0.f, 0.f, 0.f};

  // --- barrier-free K-loop ---
#pragma unroll
  for (int kk = 0; kk < 16; ++kk) {
    const int cur = kk & 1;
    short8 af[4];
#pragma unroll
    for (int f = 0; f < 4; ++f)
      af[f] = *(const short8*)&sA[kk * 2304 + (f * 16 + m16) * 36 + q * 8];
#pragma unroll
    for (int f = 0; f < 4; ++f)
#pragma unroll
      for (int bni = 0; bni < 8; ++bni)
        acc[f][bni] = __builtin_amdgcn_mfma_f32_16x16x32_bf16(
            af[f], bf[cur][bni], acc[f][bni], 0, 0, 0);
    if (kk < 14) loadB(kk + 2, cur);
  }
  __syncthreads();  // all waves done reading sA; safe to reuse as tp

  // ---- epilogue: tanh(acc+b2) -> transpose LDS -> coalesced stores ----
  {
    float b2v[8];
#pragma unroll
    for (int bni = 0; bni < 8; ++bni)
      b2v[bni] = b2[ke * ND + wn * 128 + bni * 16 + m16];
#pragma unroll
    for (int f = 0; f < 4; ++f)
#pragma unroll
      for (int rr = 0; rr < 4; ++rr) {
        int row = f * 16 + q * 4 + rr;
#pragma unroll
        for (int bni = 0; bni < 8; ++bni)
          tp[row * 524 + wn * 128 + bni * 16 + m16] =
              f2bf(fast_tanh(acc[f][bni][rr] + b2v[bni]));
      }
  }
  __syncthreads();
#pragma unroll
  for (int it = 0; it < 16; ++it) {
    int idx = it * 256 + t;
    int row = idx >> 6;           // 64 rows
    int c8 = (idx & 63) * 8;      // 64 x 8 = 512 cols
    *(uint4*)&h2raw[((size_t)(m0 + row) * NK + ke) * ND + c8] =
        *(uint4*)&tp[row * 524 + c8];
  }
}

// ---------------------------- LN + gate + plane-sum + x_prime ----
__global__ __launch_bounds__(256) void k_final(
    const ushort* __restrict__ h2raw,         // [B][K][512]
    const float* __restrict__ gates,          // [B][16]
    const float* __restrict__ x_l,            // [B][8]
    const float* __restrict__ ln_g, const float* __restrict__ ln_b,
    const float* __restrict__ theta0,         // [512]
    float* __restrict__ out) {
  const int t = threadIdx.x;
  const int l = t & 63;
  const int b = blockIdx.x * 4 + (t >> 6);
  const int d0 = l * 8;
  const ushort* P = h2raw + (size_t)b * NK * ND + d0;
  uint4 raw[16];
#pragma unroll
  for (int k = 0; k < NK; ++k) raw[k] = *(const uint4*)&P[k * ND];
  float g[8], bb[8], acc[8];
  *(float4*)&g[0] = *(const float4*)&ln_g[d0];
  *(float4*)&g[4] = *(const float4*)&ln_g[d0 + 4];
  *(float4*)&bb[0] = *(const float4*)&ln_b[d0];
  *(float4*)&bb[4] = *(const float4*)&ln_b[d0 + 4];
#pragma unroll
  for (int j = 0; j < 8; ++j) acc[j] = 0.f;
#pragma unroll
  for (int k = 0; k < NK; ++k) {
    const ushort* hp = (const ushort*)&raw[k];
    float v[8];
#pragma unroll
    for (int j = 0; j < 8; ++j) v[j] = bf2f(hp[j]);
    float s = 0.f, s2 = 0.f;
#pragma unroll
    for (int j = 0; j < 8; ++j) { s += v[j]; s2 += v[j] * v[j]; }
#pragma unroll
    for (int off = 1; off < 64; off <<= 1) {
      s += __shfl_xor(s, off, 64);
      s2 += __shfl_xor(s2, off, 64);
    }
    float mu = s * (1.f / 512.f);
    float var = s2 * (1.f / 512.f) - mu * mu;
    float rs = __builtin_amdgcn_rsqf(var + 1e-5f);
    float gate = gates[b * NK + k];
    float a = gate * rs;
#pragma unroll
    for (int j = 0; j < 8; ++j)
      acc[j] += a * g[j] * (v[j] - mu) + gate * bb[j];
  }
  float th[8];
  *(float4*)&th[0] = *(const float4*)&theta0[d0];
  *(float4*)&th[4] = *(const float4*)&theta0[d0 + 4];
#pragma unroll
  for (int j = 0; j < 8; ++j) th[j] += acc[j];
  float* thp = out + (size_t)NB * 64 + (size_t)b * ND + d0;
  *(float4*)&thp[0] = *(float4*)&th[0];
  *(float4*)&thp[4] = *(float4*)&th[4];
  const float xl = x_l[b * 8 + (l >> 3)];
  float p[8];
#pragma unroll
  for (int j = 0; j < 8; ++j) p[j] = xl * th[j];
  for (int off = 8; off < 64; off <<= 1)
#pragma unroll
    for (int j = 0; j < 8; ++j) p[j] += __shfl_xor(p[j], off, 64);
  if (l < 8) {
    float* xp = out + (size_t)b * 64 + l * 8;
    *(float4*)&xp[0] = *(float4*)&p[0];
    *(float4*)&xp[4] = *(float4*)&p[4];
  }
}

// ----------------------------------------------------------------- launch ----
extern "C" void kernel_launch(void* const* d_in, const int* in_sizes, int n_in,
                              void* d_out, int out_size, void* d_ws, size_t ws_size,
                              hipStream_t stream) {
  const float* h_prev = (const float*)d_in[0];
  const float* x_l    = (const float*)d_in[1];
  const float* x_ext  = (const float*)d_in[2];
  const float* mw1    = (const float*)d_in[3];
  const float* mb1    = (const float*)d_in[4];
  const float* mw2    = (const float*)d_in[5];
  const float* mb2    = (const float*)d_in[6];
  const float* gw1    = (const float*)d_in[7];
  const float* gb1    = (const float*)d_in[8];
  const float* gw2    = (const float*)d_in[9];
  const float* gb2    = (const float*)d_in[10];
  const float* ln_g   = (const float*)d_in[11];
  const float* ln_b   = (const float*)d_in[12];
  const float* th0    = (const float*)d_in[13];
  float* out = (float*)d_out;

  char* ws = (char*)d_ws;
  float* gates = (float*)ws;                                        // 256 KB
  ushort* B2    = (ushort*)(ws + (1u << 18));                       // 8 MB
  ushort* h2raw = (ushort*)(ws + (1u << 18) + (16u << 20));         // 64 MB

  hipLaunchKernelGGL(k_prep, dim3(1536), dim3(256), 0, stream,
                     mw2, h_prev, gw1, gb1, gw2, gb2, B2, gates);
  hipLaunchKernelGGL(k_gemm, dim3(1024), dim3(256), 0, stream,
                     x_ext, mw1, mb1, B2, mb2, h2raw);
  hipLaunchKernelGGL(k_final, dim3(NB / 4), dim3(256), 0, stream,
                     h2raw, gates, x_l, ln_g, ln_b, th0, out);
}